// Round 5
// baseline (180.337 us; speedup 1.0000x reference)
//
#include <hip/hip_runtime.h>
#include <math.h>

#define BATCH    2
#define SEQ      2048
#define DIM      1024
#define HEADS    16
#define HEAD_DIM 64
#define K_NEI    64
#define QKV_DIM  3072
#define MROWS    (BATCH * SEQ)   // 4096
#define ATT_SCALE 0.125f
#define CHUNK    16              // members per chunk = one MFMA M-tile
#define MAXCH    2048            // worst case: all groups singleton

typedef _Float16 half8  __attribute__((ext_vector_type(8)));
typedef _Float16 half4  __attribute__((ext_vector_type(4)));
typedef _Float16 half2t __attribute__((ext_vector_type(2)));
typedef float    floatx4 __attribute__((ext_vector_type(4)));

__device__ inline void async_copy16(const void* g, void* l) {
  __builtin_amdgcn_global_load_lds(
      (const __attribute__((address_space(1))) unsigned int*)g,
      (__attribute__((address_space(3))) unsigned int*)l, 16, 0, 0);
}

// fused fp32 -> f16 cast of three tensors (sizes in float4 groups)
__global__ __launch_bounds__(256)
void cast3(const float* __restrict__ a, int na4,
           const float* __restrict__ b, int nb4,
           const float* __restrict__ c, int nc4,
           _Float16* __restrict__ oa, _Float16* __restrict__ ob,
           _Float16* __restrict__ oc) {
  const int total = na4 + nb4 + nc4;
  for (int i = blockIdx.x * blockDim.x + threadIdx.x; i < total;
       i += gridDim.x * blockDim.x) {
    const float* src; _Float16* dst; int idx;
    if (i < na4)            { src = a; dst = oa; idx = i; }
    else if (i < na4 + nb4) { src = b; dst = ob; idx = i - na4; }
    else                    { src = c; dst = oc; idx = i - na4 - nb4; }
    float4 v = *(const float4*)(src + (size_t)idx * 4);
    half4 o;
    o[0] = (_Float16)v.x; o[1] = (_Float16)v.y;
    o[2] = (_Float16)v.z; o[3] = (_Float16)v.w;
    *(half4*)(dst + (size_t)idx * 4) = o;
  }
}

// C[m,n] = sum_k A[m,k]*B[n,k] + bias[n]; A:[M,K] f16, B:[N,K] f16.
template<int BM, int BN, bool HALF_OUT>
__global__ __launch_bounds__(256)
void gemm_bt_f16(const _Float16* __restrict__ A, const _Float16* __restrict__ B,
                 const float* __restrict__ bias, void* __restrict__ Cv,
                 int M, int N, int K) {
  constexpr int FI = BM / 32;
  constexpr int FJ = BN / 32;
  constexpr int CA = BM / 64;
  constexpr int CB = BN / 64;
  __shared__ _Float16 As[2 * BM * 32];
  __shared__ _Float16 Bs[2 * BN * 32];

  const int tid  = threadIdx.x;
  const int lane = tid & 63;
  const int w    = tid >> 6;
  const int wr   = w >> 1;
  const int wc   = w & 1;
  const int bm   = blockIdx.y * BM;
  const int bn   = blockIdx.x * BN;

  const int srow = w * 16 + (lane >> 2);
  const int scol = (lane & 3) * 8;
  const _Float16* ga = A + (size_t)(bm + srow) * K + scol;
  const _Float16* gb = B + (size_t)(bn + srow) * K + scol;

  const int frow = lane & 15;
  const int fk   = (lane >> 4) * 8;

  floatx4 acc[FI][FJ] = {};

  for (int k0 = 0; k0 < K; k0 += 64) {
#pragma unroll
    for (int sub = 0; sub < 2; sub++) {
      const int kk = k0 + sub * 32;
#pragma unroll
      for (int i = 0; i < CA; i++)
        async_copy16(ga + (size_t)(i * 64) * K + kk,
                     As + sub * BM * 32 + w * 512 + i * 2048);
#pragma unroll
      for (int i = 0; i < CB; i++)
        async_copy16(gb + (size_t)(i * 64) * K + kk,
                     Bs + sub * BN * 32 + w * 512 + i * 2048);
    }
    __syncthreads();

#pragma unroll
    for (int sub = 0; sub < 2; sub++) {
      half8 af[FI], bf[FJ];
#pragma unroll
      for (int i = 0; i < FI; i++)
        af[i] = *(const half8*)&As[sub * BM * 32 + (wr * (BM / 2) + i * 16 + frow) * 32 + fk];
#pragma unroll
      for (int j = 0; j < FJ; j++)
        bf[j] = *(const half8*)&Bs[sub * BN * 32 + (wc * (BN / 2) + j * 16 + frow) * 32 + fk];
#pragma unroll
      for (int i = 0; i < FI; i++)
#pragma unroll
        for (int j = 0; j < FJ; j++) {
          if (HALF_OUT)
            acc[i][j] = __builtin_amdgcn_mfma_f32_16x16x32_f16(bf[j], af[i], acc[i][j], 0, 0, 0);
          else
            acc[i][j] = __builtin_amdgcn_mfma_f32_16x16x32_f16(af[i], bf[j], acc[i][j], 0, 0, 0);
        }
    }
    __syncthreads();
  }

  if (HALF_OUT) {
    _Float16* C = (_Float16*)Cv;
    const int mloc = lane & 15;
    const int nloc = (lane >> 4) * 4;
#pragma unroll
    for (int j = 0; j < FJ; j++) {
      const int gcol = bn + wc * (BN / 2) + j * 16 + nloc;
      float4 bj = *(const float4*)(bias + gcol);
#pragma unroll
      for (int i = 0; i < FI; i++) {
        const int grow = bm + wr * (BM / 2) + i * 16 + mloc;
        half4 hv;
        hv[0] = (_Float16)(acc[i][j][0] + bj.x);
        hv[1] = (_Float16)(acc[i][j][1] + bj.y);
        hv[2] = (_Float16)(acc[i][j][2] + bj.z);
        hv[3] = (_Float16)(acc[i][j][3] + bj.w);
        *(half4*)(C + (size_t)grow * N + gcol) = hv;
      }
    }
  } else {
    float* C = (float*)Cv;
    const int crow = (lane >> 4) * 4;
    const int ccol = lane & 15;
#pragma unroll
    for (int j = 0; j < FJ; j++) {
      const int gcol = bn + wc * (BN / 2) + j * 16 + ccol;
      const float bj = bias[gcol];
#pragma unroll
      for (int i = 0; i < FI; i++) {
        const int grow = bm + wr * (BM / 2) + i * 16 + crow;
        float* cp = C + (size_t)grow * N + gcol;
#pragma unroll
        for (int r = 0; r < 4; r++)
          cp[(size_t)r * N] = acc[i][j][r] + bj;
      }
    }
  }
}

// ---------------------------------------------------------------------------
// Grouping phase A (parallel): gq[q] = leader iff routes row identical to
// leader's row (verified), else q.
// ---------------------------------------------------------------------------
__global__ __launch_bounds__(64)
void group_map(const int* __restrict__ routes, int* __restrict__ gq) {
  const int q = blockIdx.x * 64 + threadIdx.x;
  if (q >= SEQ) return;
  const int lead = routes[q * K_NEI];
  bool same = (lead >= 0) && (lead < SEQ);
  if (same && lead != q) {
    const int4* a = (const int4*)(routes + q * K_NEI);
    const int4* b = (const int4*)(routes + lead * K_NEI);
#pragma unroll
    for (int t = 0; t < 16; t++) {
      int4 x = a[t], y = b[t];
      same = same && (x.x == y.x) && (x.y == y.y) && (x.z == y.z) && (x.w == y.w);
    }
  }
  gq[q] = same ? lead : q;
}

// ---------------------------------------------------------------------------
// Grouping phase B (1 block, LDS-only): count, prefix-sum, emit chunks of
// <=CHUNK members, scatter member list.
// ---------------------------------------------------------------------------
__global__ __launch_bounds__(256)
void group_emit(const int* __restrict__ gq, int* __restrict__ gmem,
                int* __restrict__ chunks, int* __restrict__ meta) {
  __shared__ int cnt[SEQ];
  __shared__ int base[SEQ];
  __shared__ int warpsum[8];
  __shared__ int nch_sm;
  const int tid = threadIdx.x;

  for (int i = tid; i < SEQ; i += 256) cnt[i] = 0;
  if (tid == 0) nch_sm = 0;
  __syncthreads();

  for (int q = tid; q < SEQ; q += 256) atomicAdd(&cnt[gq[q]], 1);
  __syncthreads();

  int local[8];
  int s = 0;
#pragma unroll
  for (int k = 0; k < 8; k++) { local[k] = s; s += cnt[tid * 8 + k]; }
  const int lane = tid & 63, wv = tid >> 6;
  int sc = s;
#pragma unroll
  for (int off = 1; off < 64; off <<= 1) {
    int t2 = __shfl_up(sc, off);
    if (lane >= off) sc += t2;
  }
  if (lane == 63) warpsum[wv] = sc;
  __syncthreads();
  int wvoff = 0;
  for (int k = 0; k < wv; k++) wvoff += warpsum[k];
  const int thrbase = wvoff + sc - s;
#pragma unroll
  for (int k = 0; k < 8; k++) base[tid * 8 + k] = thrbase + local[k];
  __syncthreads();

  for (int gg = tid; gg < SEQ; gg += 256) {
    const int c = cnt[gg];
    if (c > 0) {
      const int nchk = (c + CHUNK - 1) / CHUNK;
      const int slot = atomicAdd(&nch_sm, nchk);
      for (int k2 = 0; k2 < nchk; k2++) {
        const int sidx = slot + k2;
        if (sidx < MAXCH) {
          const int len = min(CHUNK, c - k2 * CHUNK);
          chunks[2 * sidx]     = gg;
          chunks[2 * sidx + 1] = (base[gg] + k2 * CHUNK) | (len << 16);
        }
      }
    }
  }
  __syncthreads();
  if (tid == 0) meta[0] = min(nch_sm, MAXCH);

  for (int q = tid; q < SEQ; q += 256) {
    const int slot = atomicAdd(&base[gq[q]], 1);
    gmem[slot] = q;
  }
}

// ---------------------------------------------------------------------------
// MFMA grouped attention v3: one BLOCK per job = (chunk, b, head-group-of-4);
// 4 waves, one head each. Rounds 2-4 showed attn is bound by scattered-VMEM
// issue (64 lanes -> 64 lines per instr), invariant to traffic/occupancy.
// Fix: the 64 gathered rows are the same for ALL heads, so stage K,V for 4
// heads at once: each staging instr covers 1KB mostly-contiguous (16 lines)
// instead of 64 scattered lines -> ~4x fewer TCP probe-cycles, and jobs drop
// 8000 -> ~2000.
//   LDS K,V: [64 rows][256 halves=4 heads], 16B slots XOR-swizzled by row&7
//   (source-swizzled staging + same-involution reads, as verified in r3/r4).
//   QK/softmax/P/PV per wave: byte-equivalent port of the r3-verified math
//   (row stride 64 -> 256 halves, + w*64 head offset).
//   O: per-wave -> LDS tile (overlaid on Ps, barrier-protected) -> coalesced
//   cooperative half8 row writes.
// LDS 74KB -> 2 blocks/CU.
// ---------------------------------------------------------------------------
__global__ __launch_bounds__(256, 2)
void attn_mfma4(const _Float16* __restrict__ qkv, const int* __restrict__ routes,
                const int* __restrict__ gmem, const int* __restrict__ chunks,
                const int* __restrict__ meta, _Float16* __restrict__ ao) {
  __shared__ _Float16 Ks[64 * 256];
  __shared__ _Float16 Vs[64 * 256];
  __shared__ union {
    _Float16 P[4][1024];       // per-wave P transpose (16q x 64nei)
    _Float16 O[16 * 264];      // 16 members x 256 d (+8 pad)
  } u;

  const int tid  = threadIdx.x;
  const int w    = tid >> 6;       // wave = head within group
  const int lane = tid & 63;
  const int g    = lane >> 4;
  const int c    = lane & 15;

  const int nch   = meta[0];
  const int njobs = nch * BATCH * 4;

  const int slot  = tid & 31;      // 16B slot within a 512B row
  const int rbase = tid >> 5;      // row stepper base (0..7)

  for (int job = blockIdx.x; job < njobs; job += gridDim.x) {
    const int ch = job >> 3;
    const int b  = (job >> 2) & 1;
    const int hg = job & 3;
    const int h  = hg * 4 + w;

    const int gid   = chunks[2 * ch];
    const int mpack = chunks[2 * ch + 1];
    const int mbase = mpack & 0xFFFF;
    const int mlen  = mpack >> 16;
    const size_t rowb = (size_t)b * SEQ;
    const int hb = hg * 256;       // head-group offset within K/V section (halves)

    // ---- stage K,V: 64 rows x 512B each, 2 rows per instr, src-swizzled
#pragma unroll
    for (int i = 0; i < 8; i++) {
      const int row = i * 8 + rbase;
      const int nr  = routes[gid * K_NEI + row];
      const int sg  = slot ^ (row & 7);
      const _Float16* kp = qkv + (rowb + nr) * QKV_DIM + DIM + hb + sg * 8;
      async_copy16(kp,       Ks + (i * 256 + tid) * 8);
      async_copy16(kp + DIM, Vs + (i * 256 + tid) * 8);
    }

    // ---- Q B-frags from global (col q = lane&15, k = g*8+j [+32])
    const int qm = gmem[mbase + min(c, mlen - 1)];
    const _Float16* qrow = qkv + (rowb + qm) * QKV_DIM + h * HEAD_DIM + g * 8;
    const half8 qf0 = *(const half8*)(qrow);
    const half8 qf1 = *(const half8*)(qrow + 32);
    const half8 qf[2] = { qf0, qf1 };

    asm volatile("s_waitcnt vmcnt(0)" ::: "memory");
    __syncthreads();

    // ---- S^T = K·Q^T  (acc: row = nei m*16+g*4+reg, col = q = c)
    floatx4 st[4] = {};
#pragma unroll
    for (int s2 = 0; s2 < 2; s2++)
#pragma unroll
      for (int m = 0; m < 4; m++) {
        const int row = m * 16 + c;
        const half8 kf = *(const half8*)
            &Ks[row * 256 + w * 64 + ((((s2 << 2) + g) ^ (c & 7)) << 3)];
        st[m] = __builtin_amdgcn_mfma_f32_16x16x32_f16(kf, qf[s2], st[m], 0, 0, 0);
      }

    // ---- softmax over nei, per query column (lane&15 fixed under xor 16/32)
    float mx = st[0][0];
#pragma unroll
    for (int m = 0; m < 4; m++)
#pragma unroll
      for (int r = 0; r < 4; r++) mx = fmaxf(mx, st[m][r]);
    mx = fmaxf(mx, __shfl_xor(mx, 16));
    mx = fmaxf(mx, __shfl_xor(mx, 32));

    float p[16];
    float sum = 0.f;
#pragma unroll
    for (int m = 0; m < 4; m++)
#pragma unroll
      for (int r = 0; r < 4; r++) {
        const float e = __expf((st[m][r] - mx) * ATT_SCALE);
        p[m * 4 + r] = e;
        sum += e;
      }
    sum += __shfl_xor(sum, 16);
    sum += __shfl_xor(sum, 32);
    const float inv = 1.0f / sum;

    // ---- P -> per-wave LDS (f16, XOR-swizzled rows of 8x16B slots)
#pragma unroll
    for (int m = 0; m < 4; m++) {
      half4 ph;
      ph[0] = (_Float16)(p[m * 4 + 0] * inv);
      ph[1] = (_Float16)(p[m * 4 + 1] * inv);
      ph[2] = (_Float16)(p[m * 4 + 2] * inv);
      ph[3] = (_Float16)(p[m * 4 + 3] * inv);
      const int idx = c * 64 + (((2 * m + (g >> 1)) ^ (c & 7)) << 3) + ((g & 1) << 2);
      *(half4*)&u.P[w][idx] = ph;
    }
    asm volatile("s_waitcnt lgkmcnt(0)" ::: "memory");
    __builtin_amdgcn_sched_barrier(0);

    half8 pf[2];
#pragma unroll
    for (int s2 = 0; s2 < 2; s2++)
      pf[s2] = *(const half8*)&u.P[w][c * 64 + ((((s2 << 2) + g) ^ (c & 7)) << 3)];

    // ---- O = P·V  (acc: row = member g*4+reg, col = d = n*16+c)
    floatx4 oacc[4] = {};
#pragma unroll
    for (int n = 0; n < 4; n++) {
      const int dtop = 2 * n + (c >> 3);
#pragma unroll
      for (int s2 = 0; s2 < 2; s2++) {
        half8 vf;
#pragma unroll
        for (int j = 0; j < 8; j++) {
          const int rr = s2 * 32 + g * 8 + j;          // rr & 7 == j
          vf[j] = Vs[rr * 256 + w * 64 + ((dtop ^ j) << 3) + (c & 7)];
        }
        oacc[n] = __builtin_amdgcn_mfma_f32_16x16x32_f16(pf[s2], vf, oacc[n], 0, 0, 0);
      }
    }

    // ---- all pf reads done before O overlays P
    __syncthreads();

    // ---- O -> LDS tile (member-major), then coalesced cooperative write
#pragma unroll
    for (int n = 0; n < 4; n++)
#pragma unroll
      for (int r = 0; r < 4; r++)
        u.O[(g * 4 + r) * 264 + w * 64 + n * 16 + c] = (_Float16)oacc[n][r];
    __syncthreads();

    {
      const int i    = tid >> 4;     // member 0..15
      const int part = tid & 15;     // 16-half segment within 256
      if (i < mlen) {
        const int qr = gmem[mbase + i];
        _Float16* op = ao + (rowb + qr) * DIM + hg * 256 + part * 16;
        const _Float16* sp = &u.O[i * 264 + part * 16];
        *(half8*)op       = *(const half8*)sp;
        *(half8*)(op + 8) = *(const half8*)(sp + 8);
      }
    }
    __syncthreads();   // protect Ks/Vs/u before next job's staging
  }
}

extern "C" void kernel_launch(void* const* d_in, const int* in_sizes, int n_in,
                              void* d_out, int out_size, void* d_ws, size_t ws_size,
                              hipStream_t stream) {
  const float* x      = (const float*)d_in[0];
  const int*   routes = (const int*)  d_in[1];
  const float* qkv_w  = (const float*)d_in[2];
  const float* qkv_b  = (const float*)d_in[3];
  const float* out_w  = (const float*)d_in[4];
  const float* out_b  = (const float*)d_in[5];
  float* out = (float*)d_out;

  _Float16* qkvh = (_Float16*)d_ws;                       // 4096*3072
  _Float16* aoh  = qkvh + (size_t)MROWS * QKV_DIM;        // 4096*1024
  _Float16* xh   = aoh  + (size_t)MROWS * DIM;            // 4096*1024
  _Float16* wh   = xh   + (size_t)MROWS * DIM;            // 3072*1024
  _Float16* owh  = wh   + (size_t)QKV_DIM * DIM;          // 1024*1024

  // Grouping scratch in the tail of d_out (consumed by attn, then fully
  // overwritten by the output-projection GEMM).
  char* scr   = (char*)d_out + (size_t)out_size - 65536;
  int* gq     = (int*)scr;            // 2048 ints
  int* gmem   = gq + SEQ;             // 2048 ints (member list, CSR order)
  int* chunks = gmem + SEQ;           // 2*MAXCH ints
  int* meta   = chunks + 2 * MAXCH;   // nchunks

  group_map <<<SEQ / 64, 64, 0, stream>>>(routes, gq);
  group_emit<<<1, 256, 0, stream>>>(gq, gmem, chunks, meta);

  cast3<<<1024, 256, 0, stream>>>(x, MROWS * DIM / 4,
                                  qkv_w, QKV_DIM * DIM / 4,
                                  out_w, DIM * DIM / 4,
                                  xh, wh, owh);

  // QKV projection: 128x128 tile, 768 blocks
  {
    dim3 g(QKV_DIM / 128, MROWS / 128);
    gemm_bt_f16<128, 128, true><<<g, 256, 0, stream>>>(xh, wh, qkv_b, qkvh,
                                                       MROWS, QKV_DIM, DIM);
  }

  attn_mfma4<<<2048, 256, 0, stream>>>(qkvh, routes, gmem, chunks, meta, aoh);

  // output projection: 64x128 tile, 512 blocks
  {
    dim3 g(DIM / 128, MROWS / 64);
    gemm_bt_f16<64, 128, false><<<g, 256, 0, stream>>>(aoh, owh, out_b, out,
                                                       MROWS, DIM, DIM);
  }
}

// Round 6
// 175.662 us; speedup vs baseline: 1.0266x; 1.0266x over previous
//
#include <hip/hip_runtime.h>
#include <math.h>

#define BATCH    2
#define SEQ      2048
#define DIM      1024
#define HEADS    16
#define HEAD_DIM 64
#define K_NEI    64
#define QKV_DIM  3072
#define MROWS    (BATCH * SEQ)   // 4096
#define ATT_SCALE 0.125f
#define CHUNK    16              // members per chunk = one MFMA M-tile
#define MAXCH    2048            // worst case: all groups singleton

typedef _Float16 half8  __attribute__((ext_vector_type(8)));
typedef _Float16 half4  __attribute__((ext_vector_type(4)));
typedef float    floatx4 __attribute__((ext_vector_type(4)));

__device__ inline void async_copy16(const void* g, void* l) {
  __builtin_amdgcn_global_load_lds(
      (const __attribute__((address_space(1))) unsigned int*)g,
      (__attribute__((address_space(3))) unsigned int*)l, 16, 0, 0);
}

// ---------------------------------------------------------------------------
// fused fp32 -> f16 cast of three tensors + group_map absorbed into blocks 0-7
// (8 blocks x 256 threads = 2048 = SEQ; independent of the cast work).
// gq[q] = leader iff routes row identical to leader's row (verified), else q.
// ---------------------------------------------------------------------------
__global__ __launch_bounds__(256)
void cast3_group(const float* __restrict__ a, int na4,
                 const float* __restrict__ b, int nb4,
                 const float* __restrict__ c, int nc4,
                 _Float16* __restrict__ oa, _Float16* __restrict__ ob,
                 _Float16* __restrict__ oc,
                 const int* __restrict__ routes, int* __restrict__ gq) {
  if (blockIdx.x < 8) {
    const int q = blockIdx.x * 256 + threadIdx.x;   // 0..2047
    const int lead = routes[q * K_NEI];
    bool same = (lead >= 0) && (lead < SEQ);
    if (same && lead != q) {
      const int4* pa = (const int4*)(routes + q * K_NEI);
      const int4* pb = (const int4*)(routes + lead * K_NEI);
#pragma unroll
      for (int t = 0; t < 16; t++) {
        int4 x = pa[t], y = pb[t];
        same = same && (x.x == y.x) && (x.y == y.y) && (x.z == y.z) && (x.w == y.w);
      }
    }
    gq[q] = same ? lead : q;
  }

  const int total = na4 + nb4 + nc4;
  for (int i = blockIdx.x * blockDim.x + threadIdx.x; i < total;
       i += gridDim.x * blockDim.x) {
    const float* src; _Float16* dst; int idx;
    if (i < na4)            { src = a; dst = oa; idx = i; }
    else if (i < na4 + nb4) { src = b; dst = ob; idx = i - na4; }
    else                    { src = c; dst = oc; idx = i - na4 - nb4; }
    float4 v = *(const float4*)(src + (size_t)idx * 4);
    half4 o;
    o[0] = (_Float16)v.x; o[1] = (_Float16)v.y;
    o[2] = (_Float16)v.z; o[3] = (_Float16)v.w;
    *(half4*)(dst + (size_t)idx * 4) = o;
  }
}

// C[m,n] = sum_k A[m,k]*B[n,k] + bias[n]; A:[M,K] f16, B:[N,K] f16.
template<int BM, int BN, bool HALF_OUT>
__global__ __launch_bounds__(256)
void gemm_bt_f16(const _Float16* __restrict__ A, const _Float16* __restrict__ B,
                 const float* __restrict__ bias, void* __restrict__ Cv,
                 int M, int N, int K) {
  constexpr int FI = BM / 32;
  constexpr int FJ = BN / 32;
  constexpr int CA = BM / 64;
  constexpr int CB = BN / 64;
  __shared__ _Float16 As[2 * BM * 32];
  __shared__ _Float16 Bs[2 * BN * 32];

  const int tid  = threadIdx.x;
  const int lane = tid & 63;
  const int w    = tid >> 6;
  const int wr   = w >> 1;
  const int wc   = w & 1;
  const int bm   = blockIdx.y * BM;
  const int bn   = blockIdx.x * BN;

  const int srow = w * 16 + (lane >> 2);
  const int scol = (lane & 3) * 8;
  const _Float16* ga = A + (size_t)(bm + srow) * K + scol;
  const _Float16* gb = B + (size_t)(bn + srow) * K + scol;

  const int frow = lane & 15;
  const int fk   = (lane >> 4) * 8;

  floatx4 acc[FI][FJ] = {};

  for (int k0 = 0; k0 < K; k0 += 64) {
#pragma unroll
    for (int sub = 0; sub < 2; sub++) {
      const int kk = k0 + sub * 32;
#pragma unroll
      for (int i = 0; i < CA; i++)
        async_copy16(ga + (size_t)(i * 64) * K + kk,
                     As + sub * BM * 32 + w * 512 + i * 2048);
#pragma unroll
      for (int i = 0; i < CB; i++)
        async_copy16(gb + (size_t)(i * 64) * K + kk,
                     Bs + sub * BN * 32 + w * 512 + i * 2048);
    }
    __syncthreads();

#pragma unroll
    for (int sub = 0; sub < 2; sub++) {
      half8 af[FI], bf[FJ];
#pragma unroll
      for (int i = 0; i < FI; i++)
        af[i] = *(const half8*)&As[sub * BM * 32 + (wr * (BM / 2) + i * 16 + frow) * 32 + fk];
#pragma unroll
      for (int j = 0; j < FJ; j++)
        bf[j] = *(const half8*)&Bs[sub * BN * 32 + (wc * (BN / 2) + j * 16 + frow) * 32 + fk];
#pragma unroll
      for (int i = 0; i < FI; i++)
#pragma unroll
        for (int j = 0; j < FJ; j++) {
          if (HALF_OUT)
            acc[i][j] = __builtin_amdgcn_mfma_f32_16x16x32_f16(bf[j], af[i], acc[i][j], 0, 0, 0);
          else
            acc[i][j] = __builtin_amdgcn_mfma_f32_16x16x32_f16(af[i], bf[j], acc[i][j], 0, 0, 0);
        }
    }
    __syncthreads();
  }

  if (HALF_OUT) {
    _Float16* C = (_Float16*)Cv;
    const int mloc = lane & 15;
    const int nloc = (lane >> 4) * 4;
#pragma unroll
    for (int j = 0; j < FJ; j++) {
      const int gcol = bn + wc * (BN / 2) + j * 16 + nloc;
      float4 bj = *(const float4*)(bias + gcol);
#pragma unroll
      for (int i = 0; i < FI; i++) {
        const int grow = bm + wr * (BM / 2) + i * 16 + mloc;
        half4 hv;
        hv[0] = (_Float16)(acc[i][j][0] + bj.x);
        hv[1] = (_Float16)(acc[i][j][1] + bj.y);
        hv[2] = (_Float16)(acc[i][j][2] + bj.z);
        hv[3] = (_Float16)(acc[i][j][3] + bj.w);
        *(half4*)(C + (size_t)grow * N + gcol) = hv;
      }
    }
  } else {
    float* C = (float*)Cv;
    const int crow = (lane >> 4) * 4;
    const int ccol = lane & 15;
#pragma unroll
    for (int j = 0; j < FJ; j++) {
      const int gcol = bn + wc * (BN / 2) + j * 16 + ccol;
      const float bj = bias[gcol];
#pragma unroll
      for (int i = 0; i < FI; i++) {
        const int grow = bm + wr * (BM / 2) + i * 16 + crow;
        float* cp = C + (size_t)grow * N + gcol;
#pragma unroll
        for (int r = 0; r < 4; r++)
          cp[(size_t)r * N] = acc[i][j][r] + bj;
      }
    }
  }
}

// ---------------------------------------------------------------------------
// Grouping phase B (1 block, LDS-only): count, prefix-sum, emit chunks of
// <=CHUNK members, scatter member list.
// ---------------------------------------------------------------------------
__global__ __launch_bounds__(256)
void group_emit(const int* __restrict__ gq, int* __restrict__ gmem,
                int* __restrict__ chunks, int* __restrict__ meta) {
  __shared__ int cnt[SEQ];
  __shared__ int base[SEQ];
  __shared__ int warpsum[8];
  __shared__ int nch_sm;
  const int tid = threadIdx.x;

  for (int i = tid; i < SEQ; i += 256) cnt[i] = 0;
  if (tid == 0) nch_sm = 0;
  __syncthreads();

  for (int q = tid; q < SEQ; q += 256) atomicAdd(&cnt[gq[q]], 1);
  __syncthreads();

  int local[8];
  int s = 0;
#pragma unroll
  for (int k = 0; k < 8; k++) { local[k] = s; s += cnt[tid * 8 + k]; }
  const int lane = tid & 63, wv = tid >> 6;
  int sc = s;
#pragma unroll
  for (int off = 1; off < 64; off <<= 1) {
    int t2 = __shfl_up(sc, off);
    if (lane >= off) sc += t2;
  }
  if (lane == 63) warpsum[wv] = sc;
  __syncthreads();
  int wvoff = 0;
  for (int k = 0; k < wv; k++) wvoff += warpsum[k];
  const int thrbase = wvoff + sc - s;
#pragma unroll
  for (int k = 0; k < 8; k++) base[tid * 8 + k] = thrbase + local[k];
  __syncthreads();

  for (int gg = tid; gg < SEQ; gg += 256) {
    const int c = cnt[gg];
    if (c > 0) {
      const int nchk = (c + CHUNK - 1) / CHUNK;
      const int slot = atomicAdd(&nch_sm, nchk);
      for (int k2 = 0; k2 < nchk; k2++) {
        const int sidx = slot + k2;
        if (sidx < MAXCH) {
          const int len = min(CHUNK, c - k2 * CHUNK);
          chunks[2 * sidx]     = gg;
          chunks[2 * sidx + 1] = (base[gg] + k2 * CHUNK) | (len << 16);
        }
      }
    }
  }
  __syncthreads();
  if (tid == 0) meta[0] = min(nch_sm, MAXCH);

  for (int q = tid; q < SEQ; q += 256) {
    const int slot = atomicAdd(&base[gq[q]], 1);
    gmem[slot] = q;
  }
}

// ---------------------------------------------------------------------------
// MFMA grouped attention — round-3 best-measured structure (177.3 us total),
// verbatim, plus T5 s_setprio(1) around the two MFMA clusters (measured
// +4-7% on attention workloads, pure scheduler hint).
// One WAVE per job=(chunk, b, h); barrier-free blocks (private LDS region).
//   S^T(64nei x 16q) = K·Q^T : 8 mfma_16x16x32_f16  (contract over d)
//   softmax: per-lane column (q = lane&15), 2 shfl_xor per reduction
//   P (16q x 64nei) -> XOR-swizzled LDS -> A-frags
//   O(16q x 64d)    = P·V    : 8 mfma              (contract over nei)
// K/V staged with SOURCE-swizzled global_load_lds (linear dest); reads use
// the same involution. 18.4 KB/wave -> 4 blocks/CU.
// ---------------------------------------------------------------------------
__global__ __launch_bounds__(128)
void attn_mfma(const _Float16* __restrict__ qkv, const int* __restrict__ routes,
               const int* __restrict__ gmem, const int* __restrict__ chunks,
               const int* __restrict__ meta, _Float16* __restrict__ ao) {
  // per-wave region: Ks 4096 halves, Vs 4096, Ps 1024  (18432 B/wave)
  __shared__ _Float16 lds[2][9216];

  const int tid  = threadIdx.x;
  const int w    = tid >> 6;
  const int lane = tid & 63;
  const int g    = lane >> 4;
  const int c    = lane & 15;

  _Float16* Ks = &lds[w][0];
  _Float16* Vs = &lds[w][4096];
  _Float16* Ps = &lds[w][8192];

  const int nch    = meta[0];
  const int njobs  = nch * 32;
  const int nwaves = gridDim.x * 2;

  const int c8   = (lane & 7) ^ ((lane >> 3) & 7);  // swizzled source segment
  const int rsub = lane >> 3;

  for (int job = blockIdx.x * 2 + w; job < njobs; job += nwaves) {
    const int ch = job >> 5;
    const int bh = job & 31;
    const int h  = bh & 15;
    const int b  = bh >> 4;

    const int gid   = chunks[2 * ch];
    const int mpack = chunks[2 * ch + 1];
    const int mbase = mpack & 0xFFFF;
    const int mlen  = mpack >> 16;
    const size_t rowb = (size_t)b * SEQ;

    const int rt_l = routes[gid * K_NEI + lane];            // neighbor row, per lane
    const int qm_l = gmem[mbase + min(c, mlen - 1)];        // member q-row (idx = lane&15)

    // ---- stage K,V (64 rows x 64 halves each), source-swizzled, linear dest
#pragma unroll
    for (int k = 0; k < 8; k++) {
      const int row = __shfl(rt_l, 8 * k + rsub);
      const _Float16* kp = qkv + (rowb + row) * QKV_DIM + DIM + h * HEAD_DIM + c8 * 8;
      async_copy16(kp,       Ks + k * 512);
      async_copy16(kp + DIM, Vs + k * 512);
    }

    // ---- Q B-frags straight from global (col q = lane&15, k = g*8+j [+32])
    const _Float16* qrow = qkv + (rowb + qm_l) * QKV_DIM + h * HEAD_DIM + g * 8;
    const half8 qf0 = *(const half8*)(qrow);
    const half8 qf1 = *(const half8*)(qrow + 32);

    asm volatile("s_waitcnt vmcnt(0)" ::: "memory");

    // ---- S^T = K·Q^T  (acc: row = nei m*16+g*4+reg, col = q = c)
    floatx4 st[4] = {};
    const half8 qf[2] = { qf0, qf1 };
    __builtin_amdgcn_s_setprio(1);
#pragma unroll
    for (int s2 = 0; s2 < 2; s2++) {
#pragma unroll
      for (int m = 0; m < 4; m++) {
        const int r = m * 16 + c;
        const half8 kf =
            *(const half8*)&Ks[r * 64 + ((((s2 << 2) + g) ^ (c & 7)) << 3)];
        st[m] = __builtin_amdgcn_mfma_f32_16x16x32_f16(kf, qf[s2], st[m], 0, 0, 0);
      }
    }
    __builtin_amdgcn_s_setprio(0);

    // ---- softmax over nei, per query column (lane&15 fixed under xor 16/32)
    float mx = st[0][0];
#pragma unroll
    for (int m = 0; m < 4; m++)
#pragma unroll
      for (int r = 0; r < 4; r++) mx = fmaxf(mx, st[m][r]);
    mx = fmaxf(mx, __shfl_xor(mx, 16));
    mx = fmaxf(mx, __shfl_xor(mx, 32));

    float p[16];
    float sum = 0.f;
#pragma unroll
    for (int m = 0; m < 4; m++)
#pragma unroll
      for (int r = 0; r < 4; r++) {
        const float e = __expf((st[m][r] - mx) * ATT_SCALE);
        p[m * 4 + r] = e;
        sum += e;
      }
    sum += __shfl_xor(sum, 16);
    sum += __shfl_xor(sum, 32);
    const float inv = 1.0f / sum;

    // ---- P -> LDS (f16, XOR-swizzled rows of 8x16B slots)
#pragma unroll
    for (int m = 0; m < 4; m++) {
      half4 ph;
      ph[0] = (_Float16)(p[m * 4 + 0] * inv);
      ph[1] = (_Float16)(p[m * 4 + 1] * inv);
      ph[2] = (_Float16)(p[m * 4 + 2] * inv);
      ph[3] = (_Float16)(p[m * 4 + 3] * inv);
      const int idx = c * 64 + (((2 * m + (g >> 1)) ^ (c & 7)) << 3) + ((g & 1) << 2);
      *(half4*)&Ps[idx] = ph;
    }
    asm volatile("s_waitcnt lgkmcnt(0)" ::: "memory");

    half8 pf[2];
#pragma unroll
    for (int s2 = 0; s2 < 2; s2++)
      pf[s2] = *(const half8*)&Ps[c * 64 + ((((s2 << 2) + g) ^ (c & 7)) << 3)];

    // ---- O = P·V  (acc: row = member g*4+reg, col = d = n*16+c)
    floatx4 oa[4] = {};
    __builtin_amdgcn_s_setprio(1);
#pragma unroll
    for (int n = 0; n < 4; n++) {
      const int dtop = 2 * n + (c >> 3);
#pragma unroll
      for (int s2 = 0; s2 < 2; s2++) {
        half8 vf;
#pragma unroll
        for (int j = 0; j < 8; j++) {
          const int rr = s2 * 32 + g * 8 + j;          // rr & 7 == j
          vf[j] = Vs[rr * 64 + ((dtop ^ j) << 3) + (c & 7)];
        }
        oa[n] = __builtin_amdgcn_mfma_f32_16x16x32_f16(pf[s2], vf, oa[n], 0, 0, 0);
      }
    }
    __builtin_amdgcn_s_setprio(0);

    // ---- write O rows for valid members
#pragma unroll
    for (int r = 0; r < 4; r++) {
      const int i = g * 4 + r;
      const int qrow_i = __shfl(qm_l, i);
      if (i < mlen) {
        _Float16* op = ao + (rowb + qrow_i) * DIM + h * HEAD_DIM + c;
#pragma unroll
        for (int n = 0; n < 4; n++) op[n * 16] = (_Float16)oa[n][r];
      }
    }
  }
}

extern "C" void kernel_launch(void* const* d_in, const int* in_sizes, int n_in,
                              void* d_out, int out_size, void* d_ws, size_t ws_size,
                              hipStream_t stream) {
  const float* x      = (const float*)d_in[0];
  const int*   routes = (const int*)  d_in[1];
  const float* qkv_w  = (const float*)d_in[2];
  const float* qkv_b  = (const float*)d_in[3];
  const float* out_w  = (const float*)d_in[4];
  const float* out_b  = (const float*)d_in[5];
  float* out = (float*)d_out;

  _Float16* qkvh = (_Float16*)d_ws;                       // 4096*3072
  _Float16* aoh  = qkvh + (size_t)MROWS * QKV_DIM;        // 4096*1024
  _Float16* xh   = aoh  + (size_t)MROWS * DIM;            // 4096*1024
  _Float16* wh   = xh   + (size_t)MROWS * DIM;            // 3072*1024
  _Float16* owh  = wh   + (size_t)QKV_DIM * DIM;          // 1024*1024

  // Grouping scratch in the tail of d_out (consumed by attn, then fully
  // overwritten by the output-projection GEMM).
  char* scr   = (char*)d_out + (size_t)out_size - 65536;
  int* gq     = (int*)scr;            // 2048 ints
  int* gmem   = gq + SEQ;             // 2048 ints (member list, CSR order)
  int* chunks = gmem + SEQ;           // 2*MAXCH ints
  int* meta   = chunks + 2 * MAXCH;   // nchunks

  // cast + group_map fused (blocks 0-7 also write gq)
  cast3_group<<<1024, 256, 0, stream>>>(x, MROWS * DIM / 4,
                                        qkv_w, QKV_DIM * DIM / 4,
                                        out_w, DIM * DIM / 4,
                                        xh, wh, owh, routes, gq);

  group_emit<<<1, 256, 0, stream>>>(gq, gmem, chunks, meta);

  // QKV projection: 128x128 tile, 768 blocks
  {
    dim3 g(QKV_DIM / 128, MROWS / 128);
    gemm_bt_f16<128, 128, true><<<g, 256, 0, stream>>>(xh, wh, qkv_b, qkvh,
                                                       MROWS, QKV_DIM, DIM);
  }

  attn_mfma<<<4096, 128, 0, stream>>>(qkvh, routes, gmem, chunks, meta, aoh);

  // output projection: 64x128 tile, 512 blocks
  {
    dim3 g(DIM / 128, MROWS / 64);
    gemm_bt_f16<64, 128, false><<<g, 256, 0, stream>>>(aoh, owh, out_b, out,
                                                       MROWS, DIM, DIM);
  }
}